// Round 4
// baseline (1871.758 us; speedup 1.0000x reference)
//
#include <hip/hip_runtime.h>

#define N_NODES 50000
#define L_SCALES 4
#define E_NNZ 1600000
#define C 128
#define NL (N_NODES * L_SCALES)

#define ELL_W 64
#define OVF_CAP 8192

#define RPB 16                    // rows per bucket
#define NB (N_NODES / RPB)        // 3125 buckets (exact)
#define NSUB 8                    // per-XCD sub-regions
#define SCAP 112                  // capacity per (sub, bucket); mean 64, sigma 8
#define GROUP 4                   // buckets per workgroup in pass 2
#define BT_STRIDE 16              // pad tail counters to one per 64B line

#define SEG_SHIFT 12              // spmm column segments: 4096 rows = 2 MB of X (fits per-XCD L2)
#define NSEG 13                   // ceil(50000 / 4096)

// ---------------- Fused GEMM over all scales: Y[r,c] = sum_k feat[r,k]*W[k,c], r in [0, N*L) ----------------
// 8x8 register micro-tile per thread; A staged transposed (pad 132) + W staged, both in LDS.
// All ds_read/ds_write patterns are <=2-way bank-aliased (free). 64 FMA per 4 ds_read_b128.
__global__ __launch_bounds__(256) void gemm_all(
    const float* __restrict__ feat,   // [NL, C]
    const float* __restrict__ W,      // [C, C]
    float* __restrict__ Y)            // [NL, C]  (aliases d_out)
{
    __shared__ float As[16][132];     // As[kk][row], padded: 8.4 KB
    __shared__ float Ws[16][128];     // Ws[kk][col]: 8 KB

    int t  = threadIdx.x;
    int ty = t >> 4;                  // 0..15 -> rows ty*8..+7
    int tx = t & 15;                  // 0..15 -> cols tx*4..+3 and 64+tx*4..+3
    size_t r0 = (size_t)blockIdx.x * 128;

    float acc[8][8];
    #pragma unroll
    for (int i = 0; i < 8; ++i)
        #pragma unroll
        for (int j = 0; j < 8; ++j) acc[i][j] = 0.f;

    for (int kt = 0; kt < C; kt += 16) {
        __syncthreads();
        #pragma unroll
        for (int jj = 0; jj < 2; ++jj) {
            int q = t + 256 * jj;
            // A tile: 128 rows x 16 k, transposed into As[kk][row]
            int row = q >> 2, pc = q & 3;
            size_t r = r0 + row;
            float4 f = (r < (size_t)NL) ? ((const float4*)(feat + r * C + kt))[pc]
                                        : make_float4(0.f, 0.f, 0.f, 0.f);
            As[pc * 4 + 0][row] = f.x;
            As[pc * 4 + 1][row] = f.y;
            As[pc * 4 + 2][row] = f.z;
            As[pc * 4 + 3][row] = f.w;
            // W tile: 16 k-rows x 128 cols, natural layout
            int kr = q >> 5, wpc = q & 31;
            ((float4*)&Ws[kr][0])[wpc] = ((const float4*)(W + (size_t)(kt + kr) * C))[wpc];
        }
        __syncthreads();

        #pragma unroll
        for (int kk = 0; kk < 16; ++kk) {
            float4 a0 = *(const float4*)&As[kk][ty * 8];
            float4 a1 = *(const float4*)&As[kk][ty * 8 + 4];
            float4 w0 = *(const float4*)&Ws[kk][tx * 4];
            float4 w1 = *(const float4*)&Ws[kk][64 + tx * 4];
            float a[8] = {a0.x, a0.y, a0.z, a0.w, a1.x, a1.y, a1.z, a1.w};
            float w[8] = {w0.x, w0.y, w0.z, w0.w, w1.x, w1.y, w1.z, w1.w};
            #pragma unroll
            for (int i = 0; i < 8; ++i)
                #pragma unroll
                for (int j = 0; j < 8; ++j)
                    acc[i][j] = fmaf(a[i], w[j], acc[i][j]);
        }
    }

    #pragma unroll
    for (int i = 0; i < 8; ++i) {
        size_t r = r0 + ty * 8 + i;
        if (r < (size_t)NL) {
            float* orow = Y + r * C;
            *(float4*)(orow + tx * 4)      = make_float4(acc[i][0], acc[i][1], acc[i][2], acc[i][3]);
            *(float4*)(orow + 64 + tx * 4) = make_float4(acc[i][4], acc[i][5], acc[i][6], acc[i][7]);
        }
    }
}

// ---------------- Pass 1: partition edges into 16-row buckets, packed 8B records ----------------
__global__ __launch_bounds__(256) void partition_edges(
    const int*   __restrict__ rows,
    const int*   __restrict__ cols,
    const float* __restrict__ vals,
    uint2* __restrict__ bkt,          // [NSUB][NB][SCAP]
    int*   __restrict__ btail,        // [NSUB][NB] stride BT_STRIDE
    int* __restrict__ ovf_n, int* __restrict__ ovf_row,
    int* __restrict__ ovf_col, float* __restrict__ ovf_val)
{
    int e = blockIdx.x * 256 + threadIdx.x;
    if (e >= E_NNZ) return;
    int s = blockIdx.x & (NSUB - 1);  // heuristic XCD id: same-s blocks share an XCD L2
    int r = rows[e];
    int c = cols[e];
    float v = vals[e];
    int b = r >> 4;                   // RPB = 16
    int pos = atomicAdd(&btail[(s * NB + b) * BT_STRIDE], 1);
    if (pos < SCAP) {
        // col fits in 16 bits (N=50000 < 65536); rowlo in bits 16..19
        bkt[((size_t)s * NB + b) * SCAP + pos] =
            make_uint2((unsigned)c | ((unsigned)(r & (RPB - 1)) << 16), __float_as_uint(v));
    } else {                          // statistically never (z ~ 6 sigma); correctness fallback
        int k = atomicAdd(ovf_n, 1);
        if (k < OVF_CAP) { ovf_row[k] = r; ovf_col[k] = c; ovf_val[k] = v; }
    }
}

// ---------------- Pass 2: build packed ELL (uint2 {col, val}) in LDS, flush coalesced ----------------
__global__ __launch_bounds__(256) void ell_from_buckets(
    const uint2* __restrict__ bkt,
    const int*   __restrict__ btail,
    uint2* __restrict__ ell,          // [N][ELL_W]
    int*   __restrict__ cnt,          // [N]
    int* __restrict__ ovf_n, int* __restrict__ ovf_row,
    int* __restrict__ ovf_col, float* __restrict__ ovf_val)
{
    __shared__ __align__(16) uint2 ell_s[GROUP * RPB][ELL_W];   // 64 x 64 x 8B = 32 KB
    __shared__ int lcnt[GROUP * RPB];

    int t  = threadIdx.x;
    int b0 = blockIdx.x * GROUP;
    int r0 = b0 * RPB;

    if (t < GROUP * RPB) lcnt[t] = 0;
    __syncthreads();

    for (int g = 0; g < GROUP; ++g) {
        int b = b0 + g;
        if (b >= NB) break;           // grid covers 3128 buckets, NB=3125
        for (int s = 0; s < NSUB; ++s) {
            int n = btail[(s * NB + b) * BT_STRIDE];
            if (n > SCAP) n = SCAP;
            for (int i = t; i < n; i += 256) {
                uint2 rec = bkt[((size_t)s * NB + b) * SCAP + i];
                int lr = g * RPB + (int)(rec.x >> 16);
                int pos = atomicAdd(&lcnt[lr], 1);
                if (pos < ELL_W) {
                    ell_s[lr][pos] = make_uint2(rec.x & 0xFFFFu, rec.y);
                } else {              // row degree > 64: ~never (z ~ 5.7 sigma)
                    int k = atomicAdd(ovf_n, 1);
                    if (k < OVF_CAP) {
                        ovf_row[k] = r0 + lr;
                        ovf_col[k] = (int)(rec.x & 0xFFFFu);
                        ovf_val[k] = __uint_as_float(rec.y);
                    }
                }
            }
        }
    }
    __syncthreads();

    // Coalesced flush: 64 rows x 64 slots of uint2 = 32 KB, as uint4 (unused slots = don't-care,
    // spmm only broadcasts valid slots).
    const uint4* src = (const uint4*)&ell_s[0][0];
    for (int i = t; i < GROUP * RPB * (ELL_W / 2); i += 256) {   // 2048 uint4
        int row = r0 + (i >> 5);
        if (row < N_NODES)
            ((uint4*)ell)[(size_t)row * (ELL_W / 2) + (i & 31)] = src[i];
    }
    if (t < GROUP * RPB) {
        int row = r0 + t;
        if (row < N_NODES) cnt[row] = lcnt[t];
    }
}

// ---------------- SpMM (gather): out[row] = scale * sum_e val_e * X[col_e] ----------------
// Column-segment-ordered gather: all resident waves sweep the same ~2MB window of X,
// turning L3-bound random gathers into per-XCD L2 hits. Ballot+bit-scan per segment.
__global__ __launch_bounds__(256) void spmm_ell(
    const uint2* __restrict__ ell,
    const int*   __restrict__ cnt,
    const int*   __restrict__ ovf_n,
    const int*   __restrict__ ovf_row,
    const int*   __restrict__ ovf_col,
    const float* __restrict__ ovf_val,
    const float* __restrict__ X,          // row stride x_stride
    const float* __restrict__ row_scale,  // nullptr or theta[N]
    float*       __restrict__ out,        // row stride out_stride
    int x_stride, int out_stride)
{
    int row  = (blockIdx.x * 256 + threadIdx.x) >> 6;   // grid exact: 12500 wg x 4 rows
    int lane = threadIdx.x & 63;

    int n   = cnt[row];
    int ncl = n < ELL_W ? n : ELL_W;

    uint2 rec = make_uint2(0u, 0u);
    if (lane < ncl) rec = ell[(size_t)row * ELL_W + lane];  // masked: skip unused slots
    int mycol = (int)rec.x;
    int myval = (int)rec.y;
    int myseg = (lane < ncl) ? (mycol >> SEG_SHIFT) : 64;   // 64: never matches a segment

    float2 acc = {0.f, 0.f};
    for (int s = 0; s < NSEG; ++s) {
        unsigned long long mask = __ballot(myseg == s);     // uniform (SGPR)
        while (mask) {
            int j = __builtin_ctzll(mask);
            mask &= mask - 1;
            int   c = __builtin_amdgcn_readlane(mycol, j);  // SGPR col
            float v = __uint_as_float((unsigned)__builtin_amdgcn_readlane(myval, j));
            float2 x = ((const float2*)(X + (size_t)c * x_stride))[lane];
            acc.x = fmaf(v, x.x, acc.x);
            acc.y = fmaf(v, x.y, acc.y);
        }
    }

    int m = *ovf_n;                    // expected 0; one hot scalar read per wave
    if (m > 0) {
        if (m > OVF_CAP) m = OVF_CAP;
        for (int k = 0; k < m; ++k) {
            if (ovf_row[k] == row) {
                float v = ovf_val[k];
                float2 x = ((const float2*)(X + (size_t)ovf_col[k] * x_stride))[lane];
                acc.x = fmaf(v, x.x, acc.x);
                acc.y = fmaf(v, x.y, acc.y);
            }
        }
    }

    if (row_scale) {
        float s = row_scale[row];
        acc.x *= s;
        acc.y *= s;
    }
    ((float2*)(out + (size_t)row * out_stride))[lane] = acc;
}

extern "C" void kernel_launch(void* const* d_in, const int* in_sizes, int n_in,
                              void* d_out, int out_size, void* d_ws, size_t ws_size,
                              hipStream_t stream) {
    const int*   phi_idx  = (const int*)  d_in[0];   // [L, 2, E]
    const float* phi_val  = (const float*)d_in[1];   // [L, E]
    const int*   pinv_idx = (const int*)  d_in[2];   // [L, 2, E]
    const float* pinv_val = (const float*)d_in[3];   // [L, E]
    const float* feat     = (const float*)d_in[4];   // [N, L, C] == [NL, C]
    const float* W        = (const float*)d_in[5];   // [C, C]
    const float* theta    = (const float*)d_in[6];   // [N]
    float* out = (float*)d_out;

    // Workspace layout (~75.5 MB)
    float* Z       = (float*)d_ws;                               // N*C f32          25.6 MB
    uint2* bkt     = (uint2*)(Z + (size_t)N_NODES * C);          // NSUB*NB*SCAP     22.4 MB
    uint2* ell     = bkt + (size_t)NSUB * NB * SCAP;             // N*ELL_W uint2    25.6 MB
    int*   cnt     = (int*)(ell + (size_t)N_NODES * ELL_W);      // N                 0.2 MB
    int*   btail   = cnt + N_NODES;                              // NSUB*NB*16        1.6 MB
    int*   ovf_n   = btail + NSUB * NB * BT_STRIDE;              // 1 (adjacent for single memset)
    int*   ovf_row = ovf_n + 1;
    int*   ovf_col = ovf_row + OVF_CAP;
    float* ovf_val = (float*)(ovf_col + OVF_CAP);

    dim3 blk(256);
    int gemmGrid = (NL + 127) / 128;          // 1563 (last block: 64 rows, guarded)
    int partGrid = (E_NNZ + 255) / 256;       // 6250
    int ellGrid  = (NB + GROUP - 1) / GROUP;  // 782
    int spmmGrid = N_NODES * 64 / 256;        // 12500

    // All four scales' feat @ W in one shot, written into out (scratch; each slice
    // out[:,l,:] is consumed by scale-l spmm-1 strictly before scale-l spmm-2 overwrites it).
    gemm_all<<<gemmGrid, blk, 0, stream>>>(feat, W, out);

    for (int l = 0; l < L_SCALES; ++l) {
        // ---- Z = theta (.) (phi_inv_l @ out[:,l,:]) ----
        hipMemsetAsync(btail, 0, (NSUB * NB * BT_STRIDE + 1) * sizeof(int), stream);
        partition_edges<<<partGrid, blk, 0, stream>>>(
            pinv_idx + (size_t)l * 2 * E_NNZ,
            pinv_idx + (size_t)l * 2 * E_NNZ + E_NNZ,
            pinv_val + (size_t)l * E_NNZ,
            bkt, btail, ovf_n, ovf_row, ovf_col, ovf_val);
        ell_from_buckets<<<ellGrid, blk, 0, stream>>>(
            bkt, btail, ell, cnt, ovf_n, ovf_row, ovf_col, ovf_val);
        spmm_ell<<<spmmGrid, blk, 0, stream>>>(
            ell, cnt, ovf_n, ovf_row, ovf_col, ovf_val,
            out + (size_t)l * C, theta, Z, L_SCALES * C, C);

        // ---- out[:,l,:] = phi_l @ Z ----
        hipMemsetAsync(btail, 0, (NSUB * NB * BT_STRIDE + 1) * sizeof(int), stream);
        partition_edges<<<partGrid, blk, 0, stream>>>(
            phi_idx + (size_t)l * 2 * E_NNZ,
            phi_idx + (size_t)l * 2 * E_NNZ + E_NNZ,
            phi_val + (size_t)l * E_NNZ,
            bkt, btail, ovf_n, ovf_row, ovf_col, ovf_val);
        ell_from_buckets<<<ellGrid, blk, 0, stream>>>(
            bkt, btail, ell, cnt, ovf_n, ovf_row, ovf_col, ovf_val);
        spmm_ell<<<spmmGrid, blk, 0, stream>>>(
            ell, cnt, ovf_n, ovf_row, ovf_col, ovf_val,
            Z, nullptr, out + (size_t)l * C, C, L_SCALES * C);
    }
}